// Round 1
// baseline (47.525 us; speedup 1.0000x reference)
//
#include <hip/hip_runtime.h>

#define CI 32
#define CO 32
#define PD 64
#define QDIM 1024
#define M_TOTAL (32*4096)
#define WG_THREADS 512
#define NBLK 256
#define TILE_M 64
#define NT ((M_TOTAL/TILE_M)/NBLK)   // 8 iterations per WG

typedef float  f32x4  __attribute__((ext_vector_type(4)));
typedef __bf16 bf16x8 __attribute__((ext_vector_type(8)));
typedef __bf16 bf16x4 __attribute__((ext_vector_type(4)));

#define PL_STRIDE 72   // 64 bf16 + 8 pad -> conflict-free A-frag ds_read_b128
#define XL_STRIDE 72   // 64 f32 + 8 pad  -> <=2-way on epilogue ds_read_b128

__global__ __launch_bounds__(WG_THREADS, 2)
void cond_dense_kernel(const float* __restrict__ Xg, const float* __restrict__ Pg,
                       const float* __restrict__ Wk, float* __restrict__ outg)
{
    __shared__ __bf16 Pl[TILE_M * PL_STRIDE];
    __shared__ float  Xl[CI * XL_STRIDE];

    const int tid = threadIdx.x;
    const int l   = tid & 63;
    const int w   = tid >> 6;   // wave 0..7, owns outputs o = 4w..4w+3
    const int h   = l >> 4;     // 0..3  (k-group for A/B frags; row-group for C)
    const int c   = l & 15;     // MFMA col index
    const int di  = c >> 2;     // i (mod 4) slot
    const int dq  = c & 3;      // o (mod 4) slot

    // ---- one-time: B fragments (Wk columns) -> registers, bf16 ----
    // n-tile t covers columns q = (4t+di)*32 + 4w+dq  (i = 4t+di, o = 4w+dq)
    bf16x8 bfrag[8][2];
#pragma unroll
    for (int t = 0; t < 8; ++t) {
        const int q = (4*t + di) * CO + 4*w + dq;
#pragma unroll
        for (int s = 0; s < 2; ++s) {
            bf16x8 f;
#pragma unroll
            for (int j = 0; j < 8; ++j) {
                const int k = s*32 + h*8 + j;
                f[j] = (__bf16)Wk[k * QDIM + q];
            }
            bfrag[t][s] = f;
        }
    }

    // ---- staging assignments (coalesced f32x4 global reads) ----
    const int prow = tid >> 4;        // P rows 0..31 (and +32)
    const int pcol = (tid & 15) * 4;
    const int xrow = tid >> 3;        // X rows 0..63
    const int xcol = (tid & 7) * 4;

    f32x4 pr0, pr1, xr;
    auto load_stage = [&](int tile) {
        const float* Pb = Pg + (size_t)tile * TILE_M * PD;
        const float* Xb = Xg + (size_t)tile * TILE_M * CI;
        pr0 = *(const f32x4*)(Pb + prow * PD + pcol);
        pr1 = *(const f32x4*)(Pb + (prow + 32) * PD + pcol);
        xr  = *(const f32x4*)(Xb + xrow * CI + xcol);
    };

    const int tile0 = blockIdx.x * NT;
    load_stage(tile0);

    for (int it = 0; it < NT; ++it) {
        const int tile = tile0 + it;
        __syncthreads();                       // previous iter done reading LDS
        {   // write stage: P -> bf16 LDS, X -> transposed f32 LDS
            bf16x4 a0, a1;
#pragma unroll
            for (int j = 0; j < 4; ++j) { a0[j] = (__bf16)pr0[j]; a1[j] = (__bf16)pr1[j]; }
            *(bf16x4*)(&Pl[prow * PL_STRIDE + pcol])        = a0;
            *(bf16x4*)(&Pl[(prow + 32) * PL_STRIDE + pcol]) = a1;
#pragma unroll
            for (int j = 0; j < 4; ++j) Xl[(xcol + j) * XL_STRIDE + xrow] = xr[j];
        }
        __syncthreads();
        if (it + 1 < NT) load_stage(tile + 1); // prefetch: HBM latency under compute

        float* outp = outg + (size_t)tile * TILE_M * CO;
#pragma unroll
        for (int sub = 0; sub < 4; ++sub) {
            const int m0 = sub * 16;
            // A-fragments: row = m0+c, k = s*32 + h*8 + j
            bf16x8 af0 = *(const bf16x8*)(&Pl[(m0 + c) * PL_STRIDE + h*8]);
            bf16x8 af1 = *(const bf16x8*)(&Pl[(m0 + c) * PL_STRIDE + 32 + h*8]);

            f32x4 acc[8] = {};
#pragma unroll
            for (int t = 0; t < 8; ++t) {
                acc[t] = __builtin_amdgcn_mfma_f32_16x16x32_bf16(af0, bfrag[t][0], acc[t], 0, 0, 0);
                acc[t] = __builtin_amdgcn_mfma_f32_16x16x32_bf16(af1, bfrag[t][1], acc[t], 0, 0, 0);
            }
            // epilogue: out[m, 4w+dq] = sum_i relu(W[m,i,4w+dq]) * X[m,i]
            // lane holds W rows m0+h*4+r, i = 4t+di; X read transposed (4 m's per b128)
            f32x4 part = {};
#pragma unroll
            for (int t = 0; t < 8; ++t) {
                const int i = 4*t + di;
                f32x4 xv = *(const f32x4*)(&Xl[i * XL_STRIDE + m0 + h*4]);
#pragma unroll
                for (int r = 0; r < 4; ++r)
                    part[r] += fmaxf(acc[t][r], 0.0f) * xv[r];
            }
#pragma unroll
            for (int r = 0; r < 4; ++r) {       // reduce over di (lane bits 2,3)
                float v = part[r];
                v += __shfl_xor(v, 4);
                v += __shfl_xor(v, 8);
                part[r] = v;
            }
            // lane (h,di,dq) writes row m0+4h+di, col 4w+dq (component r=di)
            const float v = (di == 0) ? part[0] : (di == 1) ? part[1]
                          : (di == 2) ? part[2] : part[3];
            outp[(m0 + h*4 + di) * CO + w*4 + dq] = v;
        }
    }
}

extern "C" void kernel_launch(void* const* d_in, const int* in_sizes, int n_in,
                              void* d_out, int out_size, void* d_ws, size_t ws_size,
                              hipStream_t stream)
{
    const float* X  = (const float*)d_in[0];
    const float* P  = (const float*)d_in[1];
    const float* Wk = (const float*)d_in[2];
    float* out = (float*)d_out;
    cond_dense_kernel<<<dim3(NBLK), dim3(WG_THREADS), 0, stream>>>(X, P, Wk, out);
}